// Round 10
// baseline (230.425 us; speedup 1.0000x reference)
//
#include <hip/hip_runtime.h>
#include <hip/hip_bf16.h>

typedef __bf16 bf16_t;
typedef __bf16 bf16x4 __attribute__((ext_vector_type(4)));
typedef __bf16 bf16x8 __attribute__((ext_vector_type(8)));
typedef float f32x4 __attribute__((ext_vector_type(4)));
typedef float f32x8 __attribute__((ext_vector_type(8)));

#define MFMA16(a, b, c) __builtin_amdgcn_mfma_f32_16x16x32_bf16((a), (b), (c), 0, 0, 0)

#if __has_builtin(__builtin_amdgcn_exp2f)
#define EXP2(x) __builtin_amdgcn_exp2f(x)
#else
#define EXP2(x) exp2f(x)
#endif

// Problem constants: B=2, C=512, H=W=64, N=4096, heads=8, dh=64
#define NPIX 4096
#define CDIM 512
// q pre-scale: dh^-0.5 * log2(e) so softmax is a bare exp2
#define QSCALE 0.1803368801111744f

// Workgroup barrier that waits ONLY on LDS ops (lgkmcnt), not on in-flight
// global loads (vmcnt). Safe here because all LDS staging is register-
// sourced: the consumer-side vmcnt waits are auto-inserted by the compiler
// at the register use. __syncthreads would drain vmcnt(0) and defeat the
// cross-iteration global prefetch (the ~40% stall at the R9 plateau).
__device__ __forceinline__ void barrier_lgkm() {
  asm volatile("s_waitcnt lgkmcnt(0)" ::: "memory");
  __builtin_amdgcn_s_barrier();
  asm volatile("" ::: "memory");
}

// Wave-uniform dtype self-detect (see earlier rounds).
__device__ __forceinline__ bool detect_f32(const void* p) {
  const unsigned short* u = (const unsigned short*)p;
  int lane = threadIdx.x & 63;
  int f = 0;
#pragma unroll
  for (int j = 0; j < 4; ++j) {
    int e = (u[lane * 4 + j] >> 7) & 0xFF;
    f |= (e >= 138) ? 1 : 0;
  }
  return __ballot(f) != 0ull;
}

// ---------------------------------------------------------------------------
// Kernel 1: depthwise 3x3 conv, pad=1.  x (B,C,64,64) -> y_t (B, N, C)
// bf16x8 coalesced staging; LDS row stride 194 elems (conflict-free).
// ---------------------------------------------------------------------------
__global__ __launch_bounds__(256) void dwconv_kernel(
    const void* __restrict__ x_, const void* __restrict__ dww_,
    bf16_t* __restrict__ yt) {
  __shared__ bf16_t xs[64 * 194];  // [c][r*64 + w], stride 194
  __shared__ float wsh[64 * 9];
  const bool f32m = detect_f32(x_);
  int bidx = blockIdx.x;
  int c0 = (bidx & 7) << 6;
  int h = (bidx >> 3) & 63;
  int b = bidx >> 9;
  int tid = threadIdx.x;

  for (int i = tid; i < 576; i += 256)
    wsh[i] = f32m ? ((const float*)dww_)[c0 * 9 + i]
                  : (float)((const bf16_t*)dww_)[c0 * 9 + i];

  const size_t xoff = ((size_t)b * CDIM + c0) * NPIX;
#pragma unroll
  for (int r = 0; r < 3; ++r) {
    int hh = h + r - 1;
    bool ok = (unsigned)hh < 64u;
#pragma unroll
    for (int it = 0; it < 2; ++it) {
      int idx2 = tid + it * 256;
      int c = idx2 >> 3, ch = idx2 & 7;
      bf16x8 v = {};
      if (ok) {
        size_t gi = xoff + (size_t)c * NPIX + (size_t)hh * 64 + ch * 8;
        if (f32m) {
          const float* p = (const float*)x_ + gi;
          float4 t0 = *(const float4*)p;
          float4 t1 = *(const float4*)(p + 4);
          v[0] = (bf16_t)t0.x; v[1] = (bf16_t)t0.y;
          v[2] = (bf16_t)t0.z; v[3] = (bf16_t)t0.w;
          v[4] = (bf16_t)t1.x; v[5] = (bf16_t)t1.y;
          v[6] = (bf16_t)t1.z; v[7] = (bf16_t)t1.w;
        } else {
          v = *(const bf16x8*)((const bf16_t*)x_ + gi);
        }
      }
      union { bf16x8 v8; unsigned u[4]; } uu;
      uu.v8 = v;
      unsigned* dst = (unsigned*)&xs[c * 194 + r * 64 + ch * 8];
      dst[0] = uu.u[0]; dst[1] = uu.u[1]; dst[2] = uu.u[2]; dst[3] = uu.u[3];
    }
  }
  __syncthreads();

  int c = tid & 63;
  int wb = tid >> 6;
  float wreg[9];
#pragma unroll
  for (int j = 0; j < 9; ++j) wreg[j] = wsh[c * 9 + j];
  const bf16_t* xrow = &xs[c * 194];
  bf16_t* ybase = yt + ((size_t)b * NPIX + h * 64) * CDIM + c0 + c;
#pragma unroll
  for (int jj = 0; jj < 16; ++jj) {
    int w = wb + 4 * jj;
    float acc = 0.f;
#pragma unroll
    for (int r = 0; r < 3; ++r) {
      float xm = (w > 0) ? (float)xrow[r * 64 + w - 1] : 0.f;
      float xc = (float)xrow[r * 64 + w];
      float xp = (w < 63) ? (float)xrow[r * 64 + w + 1] : 0.f;
      acc += xm * wreg[3 * r] + xc * wreg[3 * r + 1] + xp * wreg[3 * r + 2];
    }
    ybase[(size_t)w * CDIM] = (bf16_t)acc;
  }
}

// ---------------------------------------------------------------------------
// GEMM: D[m][n] = sum_k A[m][k] * Bt[n][k].  A: M x 512 row-major (dtype
// self-detected), 128x128 tile, BK=32, 4 waves.  Depth-2 register prefetch
// queue + double-buffered LDS + ONE lgkm-only barrier per K-iter (global
// prefetch stays in flight across barriers).
// mode 0: Bt bf16 (B,N,C); epilogue -> q (scaled QSCALE), k, vT (plain).
// mode 1: Bt bf16 (B,N,C); epilogue -> proj out + bias.
// mode 2: B from split-K=2 partials: Bt=O1, O2p, lsb (fused combine) -> proj.
// ---------------------------------------------------------------------------
__global__ __launch_bounds__(256) void gemm_kernel(
    const void* __restrict__ A_, const bf16_t* __restrict__ Bt,
    void* __restrict__ o0, bf16_t* __restrict__ o1, bf16_t* __restrict__ o2,
    const void* __restrict__ bias_, int mode,
    const bf16_t* __restrict__ O2p, const float* __restrict__ lsb) {
  const int K = 512;
  __shared__ bf16_t as[2][128 * 40];  // +8 pad per row
  __shared__ bf16_t bs[2][128 * 40];
  const bool f32m = detect_f32(A_);
  int z = blockIdx.z;
  const bf16_t* Bz = Bt + (size_t)z * NPIX * K;
  int m0 = blockIdx.y * 128;
  int n0 = blockIdx.x * 128;
  int tid = threadIdx.x;
  int lane = tid & 63;
  int wv = tid >> 6;
  int wm = wv >> 1, wn = wv & 1;
  int col = lane & 15, quad = lane >> 4;

  bf16x8 aA[2], bA[2], aB[2], bB[2];
  auto loadAB = [&](int ko, bf16x8* ap, bf16x8* bp) {
#pragma unroll
    for (int j = 0; j < 2; ++j) {
      int i = tid + j * 256;
      int row = i >> 2, kc = (i & 3) << 3;
      if (f32m) {
        const float* p = &((const float*)A_)[(size_t)(m0 + row) * K + ko + kc];
        float4 t0 = *(const float4*)p;
        float4 t1 = *(const float4*)(p + 4);
        bf16x8 av;
        av[0] = (bf16_t)t0.x; av[1] = (bf16_t)t0.y;
        av[2] = (bf16_t)t0.z; av[3] = (bf16_t)t0.w;
        av[4] = (bf16_t)t1.x; av[5] = (bf16_t)t1.y;
        av[6] = (bf16_t)t1.z; av[7] = (bf16_t)t1.w;
        ap[j] = av;
      } else {
        ap[j] = *(const bf16x8*)&(
            (const bf16_t*)A_)[(size_t)(m0 + row) * K + ko + kc];
      }
      if (mode == 2) {
        // fused split-K combine: B[n][k] = (O1+O2)[bh][n][d] / (l1+l2)[bh][n]
        int hz = ko >> 6;  // head (BK=32 chunk never straddles a head)
        size_t qi = (size_t)(z * 8 + hz) * NPIX + n0 + row;
        float invl = 1.f / (lsb[qi] + lsb[qi + 16 * (size_t)NPIX]);
        int d = (ko & 63) + kc;
        bf16x8 p1 = *(const bf16x8*)&Bt[qi * 64 + d];
        bf16x8 p2 = *(const bf16x8*)&O2p[qi * 64 + d];
        f32x8 f;
#pragma unroll
        for (int e = 0; e < 8; ++e)
          f[e] = ((float)p1[e] + (float)p2[e]) * invl;
        bp[j] = __builtin_convertvector(f, bf16x8);
      } else {
        bp[j] = *(const bf16x8*)&Bz[(size_t)(n0 + row) * K + ko + kc];
      }
    }
  };

  loadAB(0, aA, bA);
  loadAB(32, aB, bB);
  f32x4 acc[4][4] = {};
  for (int t = 0; t < 16; ++t) {
    int buf = t & 1;
#pragma unroll
    for (int j = 0; j < 2; ++j) {
      int i = tid + j * 256;
      int row = i >> 2, kc = (i & 3) << 3;
      *(bf16x8*)&as[buf][row * 40 + kc] = aA[j];
      *(bf16x8*)&bs[buf][row * 40 + kc] = bA[j];
    }
    barrier_lgkm();
#pragma unroll
    for (int j = 0; j < 2; ++j) { aA[j] = aB[j]; bA[j] = bB[j]; }
    if (t + 2 < 16) loadAB((t + 2) * 32, aB, bB);  // in flight ~2 iters
    bf16x8 af[4], bfr[4];
#pragma unroll
    for (int f = 0; f < 4; ++f) {
      af[f] = *(const bf16x8*)&as[buf][(wm * 64 + f * 16 + col) * 40 + quad * 8];
      bfr[f] = *(const bf16x8*)&bs[buf][(wn * 64 + f * 16 + col) * 40 + quad * 8];
    }
#pragma unroll
    for (int fm = 0; fm < 4; ++fm)
#pragma unroll
      for (int fn = 0; fn < 4; ++fn)
        acc[fm][fn] = MFMA16(af[fm], bfr[fn], acc[fm][fn]);
  }

  if (mode == 0) {
    int t = m0 >> 9;  // 0=q 1=k 2=v
    float scale = (t == 0) ? QSCALE : 1.0f;
    bf16_t* q0 = (bf16_t*)o0;
#pragma unroll
    for (int fm = 0; fm < 4; ++fm) {
      int mloc = m0 + wm * 64 + fm * 16 + quad * 4;  // +r gives m
      int hh = (mloc & 511) >> 6;
      int d = mloc & 63;
#pragma unroll
      for (int fn = 0; fn < 4; ++fn) {
        int n = n0 + wn * 64 + fn * 16 + col;
        if (t < 2) {
          bf16_t* dst = ((t == 0) ? q0 : o1) +
                        ((size_t)z * 8 + hh) * ((size_t)NPIX * 64) +
                        (size_t)n * 64 + d;
          union {
            ushort4 u;
            bf16_t hv[4];
          } pk;
#pragma unroll
          for (int r = 0; r < 4; ++r) pk.hv[r] = (bf16_t)(acc[fm][fn][r] * scale);
          *(ushort4*)dst = pk.u;
        } else {
          // plain coalesced V^T store (consecutive col lanes -> consecutive n)
          bf16_t* vb = o2 + ((size_t)z * 8 + hh) * ((size_t)NPIX * 64);
#pragma unroll
          for (int r = 0; r < 4; ++r)
            vb[(size_t)(d + r) * NPIX + n] = (bf16_t)acc[fm][fn][r];
        }
      }
    }
  } else {
#pragma unroll
    for (int fm = 0; fm < 4; ++fm) {
      int mloc = m0 + wm * 64 + fm * 16 + quad * 4;
#pragma unroll
      for (int r = 0; r < 4; ++r) {
        float bv = f32m ? ((const float*)bias_)[mloc + r]
                        : (float)((const bf16_t*)bias_)[mloc + r];
#pragma unroll
        for (int fn = 0; fn < 4; ++fn) {
          int n = n0 + wn * 64 + fn * 16 + col;
          size_t oi = (size_t)z * CDIM * NPIX + (size_t)(mloc + r) * NPIX + n;
          float val = acc[fm][fn][r] + bv;
          if (f32m)
            ((float*)o0)[oi] = val;
          else
            ((bf16_t*)o0)[oi] = (bf16_t)val;
        }
      }
    }
  }
}

// ---------------------------------------------------------------------------
// Kernel 3: flash attention (transposed-S, no-max softmax), 64 q-rows/wave.
// q,k: (bh, N, 64) bf16 (q pre-scaled), vt: (bh, 64, N) plain layout; PV
// slot permutation applied during LDS staging so V^T A-frags read as b128.
// Block = 256 q rows (4 waves x 64).  Depth-2 register prefetch, double-
// buffered LDS, ONE lgkm-only barrier per iter (prefetch uninterrupted).
// MODE 0: full K (256 blocks) -> normalized o_t (b,N,C).
// MODE 2: split-K=2 (512 blocks) -> unnormalized bf16 O-partials + l.
// ---------------------------------------------------------------------------
template <int MODE>
__global__ __launch_bounds__(256, 2) void attn_kernel(
    const bf16_t* __restrict__ q, const bf16_t* __restrict__ k,
    const bf16_t* __restrict__ vt, bf16_t* __restrict__ po,
    size_t posz, float* __restrict__ lsum) {
  __shared__ bf16_t ks[2 * 64 * 72];
  __shared__ bf16_t vs[2 * 64 * 72];  // V^T tile: [d][k-local, slot-permuted]
  int qt = blockIdx.x & 15;
  int bh = (blockIdx.x >> 4) & 15;
  int kh = (MODE == 2) ? (blockIdx.x >> 8) : 0;
  const int kspan = (MODE == 2) ? 32 : 64;
  int kstart = kh * kspan;
  int kend = kstart + kspan;
  int tid = threadIdx.x;
  int lane = tid & 63, wv = tid >> 6;
  int col = lane & 15, quad = lane >> 4;
  const bf16_t* qb = q + (size_t)bh * NPIX * 64;
  const bf16_t* kb = k + (size_t)bh * NPIX * 64;
  const bf16_t* vb = vt + (size_t)bh * NPIX * 64;

  // Q fragments: direct global->reg, B-operand layout [n=q][k-dim=d]
  bf16x8 qfrag[4][2];
  int qrow0 = qt * 256 + wv * 64;
#pragma unroll
  for (int sub = 0; sub < 4; ++sub)
#pragma unroll
    for (int kk = 0; kk < 2; ++kk)
      qfrag[sub][kk] = *(const bf16x8*)&qb[(size_t)(qrow0 + sub * 16 + col) * 64 +
                                           kk * 32 + quad * 8];

  // staging assignment: thread -> row (0..63), 32B chunk (t4)
  int trow = tid >> 2, t4 = tid & 3;
  bf16x8 kA0, kA1, vA0, vA1, kB0, kB1, vB0, vB1;
  auto loadKV = [&](int kc, bf16x8& k0, bf16x8& k1, bf16x8& v0, bf16x8& v1) {
    const bf16_t* kgr = &kb[(size_t)(kc * 64 + trow) * 64 + t4 * 16];
    const bf16_t* vgr = &vb[(size_t)trow * NPIX + kc * 64 + t4 * 16];
    k0 = *(const bf16x8*)kgr;
    k1 = *(const bf16x8*)(kgr + 8);
    v0 = *(const bf16x8*)vgr;
    v1 = *(const bf16x8*)(vgr + 8);
  };
  loadKV(kstart, kA0, kA1, vA0, vA1);
  loadKV(kstart + 1, kB0, kB1, vB0, vB1);

  // LDS base for permuted V staging: chunk t4 covers w=(t4&1)*16 + 0..15 of
  // 32-block (t4>>1); element group g (4 elems) lands at offset g*8+(t4&1)*4.
  int vbase = trow * 72 + (t4 >> 1) * 32 + (t4 & 1) * 4;

  f32x4 oacc[4][4] = {};
  float lsv[4] = {0.f, 0.f, 0.f, 0.f};

  for (int kc = kstart; kc < kend; ++kc) {
    bf16_t* ksb = &ks[(kc & 1) * 4608];
    bf16_t* vsb = &vs[(kc & 1) * 4608];
    *(bf16x8*)&ksb[trow * 72 + t4 * 16] = kA0;
    *(bf16x8*)&ksb[trow * 72 + t4 * 16 + 8] = kA1;
    {
      union { bf16x8 v; bf16x4 h[2]; } u0, u1;
      u0.v = vA0; u1.v = vA1;
      *(bf16x4*)&vsb[vbase] = u0.h[0];
      *(bf16x4*)&vsb[vbase + 8] = u0.h[1];
      *(bf16x4*)&vsb[vbase + 16] = u1.h[0];
      *(bf16x4*)&vsb[vbase + 24] = u1.h[1];
    }
    barrier_lgkm();

    // shift queue; issue loads for kc+2 (in flight ~2 full iterations)
    kA0 = kB0; kA1 = kB1; vA0 = vB0; vA1 = vB1;
    {
      int kcn = kc + 2;
      if (kcn >= kend) kcn = kstart;  // harmless reload
      loadKV(kcn, kB0, kB1, vB0, vB1);
    }

    // K fragments (shared across all 4 subs)
    bf16x8 kf[4][2];
#pragma unroll
    for (int nt = 0; nt < 4; ++nt)
#pragma unroll
      for (int kk = 0; kk < 2; ++kk)
        kf[nt][kk] =
            *(const bf16x8*)&ksb[(nt * 16 + col) * 72 + kk * 32 + quad * 8];
    // V^T fragments (contiguous b128; permutation already applied at staging)
    bf16x8 vf[4][2];
#pragma unroll
    for (int dt = 0; dt < 4; ++dt)
#pragma unroll
      for (int t = 0; t < 2; ++t)
        vf[dt][t] =
            *(const bf16x8*)&vsb[(dt * 16 + col) * 72 + t * 32 + quad * 8];

#pragma unroll
    for (int sub = 0; sub < 4; ++sub) {
      // S^T = K.Q^T
      f32x4 sv[4];
#pragma unroll
      for (int nt = 0; nt < 4; ++nt) {
        f32x4 s = {};
        s = MFMA16(kf[nt][0], qfrag[sub][0], s);
        s = MFMA16(kf[nt][1], qfrag[sub][1], s);
        sv[nt] = s;
      }
      // p = exp2(logits); pack P^T B-operand frags; denominator via VALU
      bf16x8 pb[2];
      float ls = 0.f;
#pragma unroll
      for (int t = 0; t < 2; ++t) {
        f32x8 pe;
#pragma unroll
        for (int half = 0; half < 2; ++half)
#pragma unroll
          for (int r = 0; r < 4; ++r)
            pe[half * 4 + r] = EXP2(sv[2 * t + half][r]);
        float s0 = pe[0] + pe[1], s1 = pe[2] + pe[3];
        float s2 = pe[4] + pe[5], s3 = pe[6] + pe[7];
        ls += (s0 + s1) + (s2 + s3);
        pb[t] = __builtin_convertvector(pe, bf16x8);
      }
      lsv[sub] += ls;
      // O^T += V^T . P^T
#pragma unroll
      for (int dt = 0; dt < 4; ++dt) {
        oacc[sub][dt] = MFMA16(vf[dt][0], pb[0], oacc[sub][dt]);
        oacc[sub][dt] = MFMA16(vf[dt][1], pb[1], oacc[sub][dt]);
      }
    }
    // no end barrier: next iter writes the other LDS buffer; reuse of this
    // buffer at kc+2 is fenced by the intervening lgkm barrier (which drains
    // this wave's DS reads too).
  }

  // denominators: each lane's partial covers its quad's k-rows
#pragma unroll
  for (int sub = 0; sub < 4; ++sub) {
    lsv[sub] += __shfl_xor(lsv[sub], 16);
    lsv[sub] += __shfl_xor(lsv[sub], 32);
  }

  if (MODE == 0) {
    int b = bh >> 3, hh = bh & 7;
#pragma unroll
    for (int sub = 0; sub < 4; ++sub) {
      float inv = 1.f / lsv[sub];
      int qrow = qrow0 + sub * 16 + col;
      bf16_t* ob = po + ((size_t)b * NPIX + qrow) * CDIM + hh * 64 + quad * 4;
#pragma unroll
      for (int dt = 0; dt < 4; ++dt) {
        union {
          ushort4 u;
          bf16_t hv[4];
        } pk;
#pragma unroll
        for (int r = 0; r < 4; ++r)
          pk.hv[r] = (bf16_t)(oacc[sub][dt][r] * inv);
        *(ushort4*)(ob + dt * 16) = pk.u;
      }
    }
  } else {
    bf16_t* pbase = po + (size_t)kh * posz;
#pragma unroll
    for (int sub = 0; sub < 4; ++sub) {
      int qrow = qrow0 + sub * 16 + col;
      bf16_t* op = pbase + ((size_t)bh * NPIX + qrow) * 64 + quad * 4;
#pragma unroll
      for (int dt = 0; dt < 4; ++dt) {
        union {
          ushort4 u;
          bf16_t hv[4];
        } pk;
#pragma unroll
        for (int r = 0; r < 4; ++r) pk.hv[r] = (bf16_t)oacc[sub][dt][r];
        *(ushort4*)(op + dt * 16) = pk.u;
      }
    }
    if (quad == 0) {
      float* lbase = lsum + (size_t)(kh * 16 + bh) * NPIX;
#pragma unroll
      for (int sub = 0; sub < 4; ++sub)
        lbase[qrow0 + sub * 16 + col] = lsv[sub];
    }
  }
}

// ---------------------------------------------------------------------------
extern "C" void kernel_launch(void* const* d_in, const int* in_sizes, int n_in,
                              void* d_out, int out_size, void* d_ws,
                              size_t ws_size, hipStream_t stream) {
  const void* x = d_in[0];
  const void* dww = d_in[1];
  const void* qkvw = d_in[2];
  const void* projw = d_in[3];
  const void* projb = d_in[4];

  bf16_t* ws = (bf16_t*)d_ws;
  const size_t SZ = (size_t)2 * NPIX * CDIM;  // 4,194,304 elems per buffer
  bf16_t* yt = ws;           // y_t (B,N,C); dead after gemm1
  bf16_t* qa = ws + SZ;      // q (b,h,n,d), pre-scaled by QSCALE
  bf16_t* ka = ws + 2 * SZ;  // k (b,h,n,d)
  bf16_t* va = ws + 3 * SZ;  // vT (b,h,d,n), plain layout

  const size_t need2 =
      5 * SZ * sizeof(bf16_t) + 2 * 16 * (size_t)NPIX * sizeof(float);

  dwconv_kernel<<<1024, 256, 0, stream>>>(x, dww, yt);
  gemm_kernel<<<dim3(32, 12, 2), 256, 0, stream>>>(
      qkvw, yt, qa, ka, va, nullptr, 0, nullptr, nullptr);

  if (ws_size >= need2) {
    bf16_t* O1 = yt;  // partial s=0 overlays yt
    bf16_t* O2 = ws + 4 * SZ;
    float* ls2 = (float*)(ws + 5 * SZ);
    attn_kernel<2><<<512, 256, 0, stream>>>(qa, ka, va, O1,
                                            (size_t)(O2 - O1), ls2);
    gemm_kernel<<<dim3(32, 4, 2), 256, 0, stream>>>(
        projw, O1, d_out, nullptr, nullptr, projb, 2, O2, ls2);
  } else {
    attn_kernel<0><<<256, 256, 0, stream>>>(qa, ka, va, yt, 0, nullptr);
    gemm_kernel<<<dim3(32, 4, 2), 256, 0, stream>>>(
        projw, yt, d_out, nullptr, nullptr, projb, 1, nullptr, nullptr);
  }
}

// Round 11
// 207.552 us; speedup vs baseline: 1.1102x; 1.1102x over previous
//
#include <hip/hip_runtime.h>
#include <hip/hip_bf16.h>

typedef __bf16 bf16_t;
typedef __bf16 bf16x4 __attribute__((ext_vector_type(4)));
typedef __bf16 bf16x8 __attribute__((ext_vector_type(8)));
typedef float f32x4 __attribute__((ext_vector_type(4)));
typedef float f32x8 __attribute__((ext_vector_type(8)));

#define MFMA16(a, b, c) __builtin_amdgcn_mfma_f32_16x16x32_bf16((a), (b), (c), 0, 0, 0)

#if __has_builtin(__builtin_amdgcn_exp2f)
#define EXP2(x) __builtin_amdgcn_exp2f(x)
#else
#define EXP2(x) exp2f(x)
#endif

// Address-space casts for global_load_lds (HBM -> LDS direct, width 16).
#define AS1(p) ((const __attribute__((address_space(1))) void*)(p))
#define AS3(p) ((__attribute__((address_space(3))) void*)(p))

// Problem constants: B=2, C=512, H=W=64, N=4096, heads=8, dh=64
#define NPIX 4096
#define CDIM 512
// q pre-scale: dh^-0.5 * log2(e) so softmax is a bare exp2
#define QSCALE 0.1803368801111744f

// Wave-uniform dtype self-detect (see earlier rounds).
__device__ __forceinline__ bool detect_f32(const void* p) {
  const unsigned short* u = (const unsigned short*)p;
  int lane = threadIdx.x & 63;
  int f = 0;
#pragma unroll
  for (int j = 0; j < 4; ++j) {
    int e = (u[lane * 4 + j] >> 7) & 0xFF;
    f |= (e >= 138) ? 1 : 0;
  }
  return __ballot(f) != 0ull;
}

// ---------------------------------------------------------------------------
// Kernel 1: depthwise 3x3 conv, pad=1.  x (B,C,64,64) -> y_t (B, N, C)
// bf16x8 coalesced staging; LDS row stride 194 elems (conflict-free).
// ---------------------------------------------------------------------------
__global__ __launch_bounds__(256) void dwconv_kernel(
    const void* __restrict__ x_, const void* __restrict__ dww_,
    bf16_t* __restrict__ yt) {
  __shared__ bf16_t xs[64 * 194];  // [c][r*64 + w], stride 194
  __shared__ float wsh[64 * 9];
  const bool f32m = detect_f32(x_);
  int bidx = blockIdx.x;
  int c0 = (bidx & 7) << 6;
  int h = (bidx >> 3) & 63;
  int b = bidx >> 9;
  int tid = threadIdx.x;

  for (int i = tid; i < 576; i += 256)
    wsh[i] = f32m ? ((const float*)dww_)[c0 * 9 + i]
                  : (float)((const bf16_t*)dww_)[c0 * 9 + i];

  const size_t xoff = ((size_t)b * CDIM + c0) * NPIX;
#pragma unroll
  for (int r = 0; r < 3; ++r) {
    int hh = h + r - 1;
    bool ok = (unsigned)hh < 64u;
#pragma unroll
    for (int it = 0; it < 2; ++it) {
      int idx2 = tid + it * 256;
      int c = idx2 >> 3, ch = idx2 & 7;
      bf16x8 v = {};
      if (ok) {
        size_t gi = xoff + (size_t)c * NPIX + (size_t)hh * 64 + ch * 8;
        if (f32m) {
          const float* p = (const float*)x_ + gi;
          float4 t0 = *(const float4*)p;
          float4 t1 = *(const float4*)(p + 4);
          v[0] = (bf16_t)t0.x; v[1] = (bf16_t)t0.y;
          v[2] = (bf16_t)t0.z; v[3] = (bf16_t)t0.w;
          v[4] = (bf16_t)t1.x; v[5] = (bf16_t)t1.y;
          v[6] = (bf16_t)t1.z; v[7] = (bf16_t)t1.w;
        } else {
          v = *(const bf16x8*)((const bf16_t*)x_ + gi);
        }
      }
      union { bf16x8 v8; unsigned u[4]; } uu;
      uu.v8 = v;
      unsigned* dst = (unsigned*)&xs[c * 194 + r * 64 + ch * 8];
      dst[0] = uu.u[0]; dst[1] = uu.u[1]; dst[2] = uu.u[2]; dst[3] = uu.u[3];
    }
  }
  __syncthreads();

  int c = tid & 63;
  int wb = tid >> 6;
  float wreg[9];
#pragma unroll
  for (int j = 0; j < 9; ++j) wreg[j] = wsh[c * 9 + j];
  const bf16_t* xrow = &xs[c * 194];
  bf16_t* ybase = yt + ((size_t)b * NPIX + h * 64) * CDIM + c0 + c;
#pragma unroll
  for (int jj = 0; jj < 16; ++jj) {
    int w = wb + 4 * jj;
    float acc = 0.f;
#pragma unroll
    for (int r = 0; r < 3; ++r) {
      float xm = (w > 0) ? (float)xrow[r * 64 + w - 1] : 0.f;
      float xc = (float)xrow[r * 64 + w];
      float xp = (w < 63) ? (float)xrow[r * 64 + w + 1] : 0.f;
      acc += xm * wreg[3 * r] + xc * wreg[3 * r + 1] + xp * wreg[3 * r + 2];
    }
    ybase[(size_t)w * CDIM] = (bf16_t)acc;
  }
}

// ---------------------------------------------------------------------------
// GEMM (m97 recipe): D[m][n] = sum_k A[m][k]*Bt[n][k].  128x128 tile, BK=32,
// unpadded [128][32] LDS tiles filled by global_load_lds width=16 (HBM->LDS
// direct, wave-uniform dest base + lane*16), single-buffered 2-barrier loop.
// Grid: blockIdx.x = m-tile (fastest; consecutive blocks share the B-tile,
// small A stays L2-resident), blockIdx.y = n-tile, z = batch.
// mode 0: epilogue -> q (scaled QSCALE), k, vT (plain coalesced).
// mode 1: epilogue -> proj out + bias.
// mode 2: B built from split-K=2 partials (register path); A still glds.
// f32 inputs fall back to register staging for A.
// ---------------------------------------------------------------------------
__global__ __launch_bounds__(256) void gemm_kernel(
    const void* __restrict__ A_, const bf16_t* __restrict__ Bt,
    void* __restrict__ o0, bf16_t* __restrict__ o1, bf16_t* __restrict__ o2,
    const void* __restrict__ bias_, int mode,
    const bf16_t* __restrict__ O2p, const float* __restrict__ lsb) {
  const int K = 512;
  __shared__ bf16_t as[128 * 32];
  __shared__ bf16_t bs[128 * 32];
  const bool f32m = detect_f32(A_);
  int z = blockIdx.z;
  const bf16_t* Bz = Bt + (size_t)z * NPIX * K;
  int m0 = blockIdx.x * 128;
  int n0 = blockIdx.y * 128;
  int tid = threadIdx.x;
  int lane = tid & 63;
  int wv = tid >> 6;
  int wm = wv >> 1, wn = wv & 1;
  int col = lane & 15, quad = lane >> 4;

  f32x4 acc[4][4] = {};
  for (int ko = 0; ko < K; ko += 32) {
    // ---- stage A tile ----
    if (!f32m) {
#pragma unroll
      for (int j = 0; j < 2; ++j) {
        int i = tid + j * 256;
        int row = i >> 2, kc = (i & 3) << 3;
        __builtin_amdgcn_global_load_lds(
            AS1(&((const bf16_t*)A_)[(size_t)(m0 + row) * K + ko + kc]),
            AS3(&as[(wv * 64 + j * 256) * 8]), 16, 0, 0);
      }
    } else {
#pragma unroll
      for (int j = 0; j < 2; ++j) {
        int i = tid + j * 256;
        int row = i >> 2, kc = (i & 3) << 3;
        const float* p = &((const float*)A_)[(size_t)(m0 + row) * K + ko + kc];
        float4 t0 = *(const float4*)p;
        float4 t1 = *(const float4*)(p + 4);
        bf16x8 av;
        av[0] = (bf16_t)t0.x; av[1] = (bf16_t)t0.y;
        av[2] = (bf16_t)t0.z; av[3] = (bf16_t)t0.w;
        av[4] = (bf16_t)t1.x; av[5] = (bf16_t)t1.y;
        av[6] = (bf16_t)t1.z; av[7] = (bf16_t)t1.w;
        *(bf16x8*)&as[row * 32 + kc] = av;
      }
    }
    // ---- stage B tile ----
    if (mode != 2) {
#pragma unroll
      for (int j = 0; j < 2; ++j) {
        int i = tid + j * 256;
        int row = i >> 2, kc = (i & 3) << 3;
        __builtin_amdgcn_global_load_lds(
            AS1(&Bz[(size_t)(n0 + row) * K + ko + kc]),
            AS3(&bs[(wv * 64 + j * 256) * 8]), 16, 0, 0);
      }
    } else {
#pragma unroll
      for (int j = 0; j < 2; ++j) {
        int i = tid + j * 256;
        int row = i >> 2, kc = (i & 3) << 3;
        int hz = ko >> 6;  // head (BK=32 chunk never straddles a head)
        size_t qi = (size_t)(z * 8 + hz) * NPIX + n0 + row;
        float invl = 1.f / (lsb[qi] + lsb[qi + 16 * (size_t)NPIX]);
        int d = (ko & 63) + kc;
        bf16x8 p1 = *(const bf16x8*)&Bt[qi * 64 + d];
        bf16x8 p2 = *(const bf16x8*)&O2p[qi * 64 + d];
        f32x8 f;
#pragma unroll
        for (int e = 0; e < 8; ++e)
          f[e] = ((float)p1[e] + (float)p2[e]) * invl;
        *(bf16x8*)&bs[row * 32 + kc] = __builtin_convertvector(f, bf16x8);
      }
    }
    __syncthreads();  // drains vmcnt (glds) + lgkmcnt (ds writes)

    bf16x8 af[4], bfr[4];
#pragma unroll
    for (int f = 0; f < 4; ++f) {
      af[f] = *(const bf16x8*)&as[(wm * 64 + f * 16 + col) * 32 + quad * 8];
      bfr[f] = *(const bf16x8*)&bs[(wn * 64 + f * 16 + col) * 32 + quad * 8];
    }
#pragma unroll
    for (int fm = 0; fm < 4; ++fm)
#pragma unroll
      for (int fn = 0; fn < 4; ++fn)
        acc[fm][fn] = MFMA16(af[fm], bfr[fn], acc[fm][fn]);
    __syncthreads();
  }

  if (mode == 0) {
    int t = m0 >> 9;  // 0=q 1=k 2=v
    float scale = (t == 0) ? QSCALE : 1.0f;
    bf16_t* q0 = (bf16_t*)o0;
#pragma unroll
    for (int fm = 0; fm < 4; ++fm) {
      int mloc = m0 + wm * 64 + fm * 16 + quad * 4;  // +r gives m
      int hh = (mloc & 511) >> 6;
      int d = mloc & 63;
#pragma unroll
      for (int fn = 0; fn < 4; ++fn) {
        int n = n0 + wn * 64 + fn * 16 + col;
        if (t < 2) {
          bf16_t* dst = ((t == 0) ? q0 : o1) +
                        ((size_t)z * 8 + hh) * ((size_t)NPIX * 64) +
                        (size_t)n * 64 + d;
          union {
            ushort4 u;
            bf16_t hv[4];
          } pk;
#pragma unroll
          for (int r = 0; r < 4; ++r) pk.hv[r] = (bf16_t)(acc[fm][fn][r] * scale);
          *(ushort4*)dst = pk.u;
        } else {
          // plain coalesced V^T store (consecutive col lanes -> consecutive n)
          bf16_t* vb = o2 + ((size_t)z * 8 + hh) * ((size_t)NPIX * 64);
#pragma unroll
          for (int r = 0; r < 4; ++r)
            vb[(size_t)(d + r) * NPIX + n] = (bf16_t)acc[fm][fn][r];
        }
      }
    }
  } else {
#pragma unroll
    for (int fm = 0; fm < 4; ++fm) {
      int mloc = m0 + wm * 64 + fm * 16 + quad * 4;
#pragma unroll
      for (int r = 0; r < 4; ++r) {
        float bv = f32m ? ((const float*)bias_)[mloc + r]
                        : (float)((const bf16_t*)bias_)[mloc + r];
#pragma unroll
        for (int fn = 0; fn < 4; ++fn) {
          int n = n0 + wn * 64 + fn * 16 + col;
          size_t oi = (size_t)z * CDIM * NPIX + (size_t)(mloc + r) * NPIX + n;
          float val = acc[fm][fn][r] + bv;
          if (f32m)
            ((float*)o0)[oi] = val;
          else
            ((bf16_t*)o0)[oi] = (bf16_t)val;
        }
      }
    }
  }
}

// ---------------------------------------------------------------------------
// Kernel 3: flash attention (transposed-S, no-max softmax), 64 q-rows/wave —
// exact R9 configuration (best measured: 75.7 us).
// ---------------------------------------------------------------------------
template <int MODE>
__global__ __launch_bounds__(256, 2) void attn_kernel(
    const bf16_t* __restrict__ q, const bf16_t* __restrict__ k,
    const bf16_t* __restrict__ vt, bf16_t* __restrict__ po,
    size_t posz, float* __restrict__ lsum) {
  __shared__ bf16_t ks[2 * 64 * 72];
  __shared__ bf16_t vs[2 * 64 * 72];  // V^T tile: [d][k-local, slot-permuted]
  int qt = blockIdx.x & 15;
  int bh = (blockIdx.x >> 4) & 15;
  int kh = (MODE == 2) ? (blockIdx.x >> 8) : 0;
  const int kspan = (MODE == 2) ? 32 : 64;
  int kstart = kh * kspan;
  int kend = kstart + kspan;
  int tid = threadIdx.x;
  int lane = tid & 63, wv = tid >> 6;
  int col = lane & 15, quad = lane >> 4;
  const bf16_t* qb = q + (size_t)bh * NPIX * 64;
  const bf16_t* kb = k + (size_t)bh * NPIX * 64;
  const bf16_t* vb = vt + (size_t)bh * NPIX * 64;

  bf16x8 qfrag[4][2];
  int qrow0 = qt * 256 + wv * 64;
#pragma unroll
  for (int sub = 0; sub < 4; ++sub)
#pragma unroll
    for (int kk = 0; kk < 2; ++kk)
      qfrag[sub][kk] = *(const bf16x8*)&qb[(size_t)(qrow0 + sub * 16 + col) * 64 +
                                           kk * 32 + quad * 8];

  int trow = tid >> 2, t4 = tid & 3;
  bf16x8 kA0, kA1, vA0, vA1, kB0, kB1, vB0, vB1;
  auto loadKV = [&](int kc, bf16x8& k0, bf16x8& k1, bf16x8& v0, bf16x8& v1) {
    const bf16_t* kgr = &kb[(size_t)(kc * 64 + trow) * 64 + t4 * 16];
    const bf16_t* vgr = &vb[(size_t)trow * NPIX + kc * 64 + t4 * 16];
    k0 = *(const bf16x8*)kgr;
    k1 = *(const bf16x8*)(kgr + 8);
    v0 = *(const bf16x8*)vgr;
    v1 = *(const bf16x8*)(vgr + 8);
  };
  loadKV(kstart, kA0, kA1, vA0, vA1);
  loadKV(kstart + 1, kB0, kB1, vB0, vB1);

  int vbase = trow * 72 + (t4 >> 1) * 32 + (t4 & 1) * 4;

  f32x4 oacc[4][4] = {};
  float lsv[4] = {0.f, 0.f, 0.f, 0.f};

  for (int kc = kstart; kc < kend; ++kc) {
    bf16_t* ksb = &ks[(kc & 1) * 4608];
    bf16_t* vsb = &vs[(kc & 1) * 4608];
    *(bf16x8*)&ksb[trow * 72 + t4 * 16] = kA0;
    *(bf16x8*)&ksb[trow * 72 + t4 * 16 + 8] = kA1;
    {
      union { bf16x8 v; bf16x4 h[2]; } u0, u1;
      u0.v = vA0; u1.v = vA1;
      *(bf16x4*)&vsb[vbase] = u0.h[0];
      *(bf16x4*)&vsb[vbase + 8] = u0.h[1];
      *(bf16x4*)&vsb[vbase + 16] = u1.h[0];
      *(bf16x4*)&vsb[vbase + 24] = u1.h[1];
    }
    __syncthreads();

    kA0 = kB0; kA1 = kB1; vA0 = vB0; vA1 = vB1;
    {
      int kcn = kc + 2;
      if (kcn >= kend) kcn = kstart;  // harmless reload
      loadKV(kcn, kB0, kB1, vB0, vB1);
    }

    bf16x8 kf[4][2];
#pragma unroll
    for (int nt = 0; nt < 4; ++nt)
#pragma unroll
      for (int kk = 0; kk < 2; ++kk)
        kf[nt][kk] =
            *(const bf16x8*)&ksb[(nt * 16 + col) * 72 + kk * 32 + quad * 8];
    bf16x8 vf[4][2];
#pragma unroll
    for (int dt = 0; dt < 4; ++dt)
#pragma unroll
      for (int t = 0; t < 2; ++t)
        vf[dt][t] =
            *(const bf16x8*)&vsb[(dt * 16 + col) * 72 + t * 32 + quad * 8];

#pragma unroll
    for (int sub = 0; sub < 4; ++sub) {
      f32x4 sv[4];
#pragma unroll
      for (int nt = 0; nt < 4; ++nt) {
        f32x4 s = {};
        s = MFMA16(kf[nt][0], qfrag[sub][0], s);
        s = MFMA16(kf[nt][1], qfrag[sub][1], s);
        sv[nt] = s;
      }
      bf16x8 pb[2];
      float ls = 0.f;
#pragma unroll
      for (int t = 0; t < 2; ++t) {
        f32x8 pe;
#pragma unroll
        for (int half = 0; half < 2; ++half)
#pragma unroll
          for (int r = 0; r < 4; ++r)
            pe[half * 4 + r] = EXP2(sv[2 * t + half][r]);
        float s0 = pe[0] + pe[1], s1 = pe[2] + pe[3];
        float s2 = pe[4] + pe[5], s3 = pe[6] + pe[7];
        ls += (s0 + s1) + (s2 + s3);
        pb[t] = __builtin_convertvector(pe, bf16x8);
      }
      lsv[sub] += ls;
#pragma unroll
      for (int dt = 0; dt < 4; ++dt) {
        oacc[sub][dt] = MFMA16(vf[dt][0], pb[0], oacc[sub][dt]);
        oacc[sub][dt] = MFMA16(vf[dt][1], pb[1], oacc[sub][dt]);
      }
    }
  }

#pragma unroll
  for (int sub = 0; sub < 4; ++sub) {
    lsv[sub] += __shfl_xor(lsv[sub], 16);
    lsv[sub] += __shfl_xor(lsv[sub], 32);
  }

  if (MODE == 0) {
    int b = bh >> 3, hh = bh & 7;
#pragma unroll
    for (int sub = 0; sub < 4; ++sub) {
      float inv = 1.f / lsv[sub];
      int qrow = qrow0 + sub * 16 + col;
      bf16_t* ob = po + ((size_t)b * NPIX + qrow) * CDIM + hh * 64 + quad * 4;
#pragma unroll
      for (int dt = 0; dt < 4; ++dt) {
        union {
          ushort4 u;
          bf16_t hv[4];
        } pk;
#pragma unroll
        for (int r = 0; r < 4; ++r)
          pk.hv[r] = (bf16_t)(oacc[sub][dt][r] * inv);
        *(ushort4*)(ob + dt * 16) = pk.u;
      }
    }
  } else {
    bf16_t* pbase = po + (size_t)kh * posz;
#pragma unroll
    for (int sub = 0; sub < 4; ++sub) {
      int qrow = qrow0 + sub * 16 + col;
      bf16_t* op = pbase + ((size_t)bh * NPIX + qrow) * 64 + quad * 4;
#pragma unroll
      for (int dt = 0; dt < 4; ++dt) {
        union {
          ushort4 u;
          bf16_t hv[4];
        } pk;
#pragma unroll
        for (int r = 0; r < 4; ++r) pk.hv[r] = (bf16_t)oacc[sub][dt][r];
        *(ushort4*)(op + dt * 16) = pk.u;
      }
    }
    if (quad == 0) {
      float* lbase = lsum + (size_t)(kh * 16 + bh) * NPIX;
#pragma unroll
      for (int sub = 0; sub < 4; ++sub)
        lbase[qrow0 + sub * 16 + col] = lsv[sub];
    }
  }
}

// ---------------------------------------------------------------------------
extern "C" void kernel_launch(void* const* d_in, const int* in_sizes, int n_in,
                              void* d_out, int out_size, void* d_ws,
                              size_t ws_size, hipStream_t stream) {
  const void* x = d_in[0];
  const void* dww = d_in[1];
  const void* qkvw = d_in[2];
  const void* projw = d_in[3];
  const void* projb = d_in[4];

  bf16_t* ws = (bf16_t*)d_ws;
  const size_t SZ = (size_t)2 * NPIX * CDIM;  // 4,194,304 elems per buffer
  bf16_t* yt = ws;           // y_t (B,N,C); dead after gemm1
  bf16_t* qa = ws + SZ;      // q (b,h,n,d), pre-scaled by QSCALE
  bf16_t* ka = ws + 2 * SZ;  // k (b,h,n,d)
  bf16_t* va = ws + 3 * SZ;  // vT (b,h,d,n), plain layout

  const size_t need2 =
      5 * SZ * sizeof(bf16_t) + 2 * 16 * (size_t)NPIX * sizeof(float);

  dwconv_kernel<<<1024, 256, 0, stream>>>(x, dww, yt);
  // m-tile fastest: consecutive blocks share the B-tile (L2 reuse)
  gemm_kernel<<<dim3(12, 32, 2), 256, 0, stream>>>(
      qkvw, yt, qa, ka, va, nullptr, 0, nullptr, nullptr);

  if (ws_size >= need2) {
    bf16_t* O1 = yt;  // partial s=0 overlays yt
    bf16_t* O2 = ws + 4 * SZ;
    float* ls2 = (float*)(ws + 5 * SZ);
    attn_kernel<2><<<512, 256, 0, stream>>>(qa, ka, va, O1,
                                            (size_t)(O2 - O1), ls2);
    gemm_kernel<<<dim3(4, 32, 2), 256, 0, stream>>>(
        projw, O1, d_out, nullptr, nullptr, projb, 2, O2, ls2);
  } else {
    attn_kernel<0><<<256, 256, 0, stream>>>(qa, ka, va, yt, 0, nullptr);
    gemm_kernel<<<dim3(4, 32, 2), 256, 0, stream>>>(
        projw, yt, d_out, nullptr, nullptr, projb, 1, nullptr, nullptr);
  }
}